// Round 1
// baseline (324.688 us; speedup 1.0000x reference)
//
#include <hip/hip_runtime.h>
#include <math.h>

// Problem constants
#define B_ROWS 16384      // 8*2048 batch rows
#define IDIM   1024
#define ODIM   1024
#define NGRID  9          // NUM_SEGMENTS + 1

#define RS_BLOCKS 1024
#define RS_ROWS   (B_ROWS / RS_BLOCKS)   // 16 rows per block

// GEMM: BM=256 rows, BN=128 real cols (x2 planes -> 256 eff), BK=64, 8 waves.
// m-slots: max sum over buckets of ceil(cnt/256) <= 64 + 9 = 73 -> 80 slots.
// Swizzle windows of 64 ids: (sub&7)=m-class (same XCD via round-robin),
// sub>>3 = n-tile (0..7) -> the 8 n-blocks of one m-tile share an XCD L2.
#define GEMM_MSLOTS 80
#define GEMM_NT     8
#define GEMM_BLOCKS (GEMM_MSLOTS * GEMM_NT)   // 640

typedef __attribute__((ext_vector_type(8))) short frag8;   // 8 x bf16 (4 VGPRs)
typedef __attribute__((ext_vector_type(4))) float f32x4;   // MFMA accumulator

typedef __attribute__((address_space(1))) void gvoid;
typedef __attribute__((address_space(3))) void lvoid;

__device__ __forceinline__ void async_cp16(const void* g, void* l) {
  // 16B/lane global->LDS DMA; LDS dest = wave-uniform base + lane*16.
  __builtin_amdgcn_global_load_lds((gvoid*)(void*)g, (lvoid*)l, 16, 0, 0);
}

__device__ __forceinline__ unsigned short f2bf(float f) {
  union { float f; unsigned u; } v; v.f = f;
  unsigned u = v.u;
  u += 0x7fffu + ((u >> 16) & 1u);      // round-to-nearest-even
  return (unsigned short)(u >> 16);
}

// Per-row hat weights: at most 2 nonzero, at segments {s, s+1}
__device__ __forceinline__ void seg_weights(float m, int& sI, float& w0, float& w1) {
  float wsum = 0.f, wg[NGRID];
#pragma unroll
  for (int g = 0; g < NGRID; g++) {
    float gv = -1.f + 0.25f * (float)g;
    float t = 1.f - fabsf(m - gv) * 4.f;   // 1/h = 4
    wg[g] = t > 0.f ? t : 0.f;
    wsum += wg[g];
  }
  int s = (int)floorf((m + 1.f) * 4.f);
  s = s < 0 ? 0 : (s > 7 ? 7 : s);
  float inv = 1.f / (wsum + 1e-8f);
  sI = s;
  w0 = wg[s] * inv;
  w1 = wg[s + 1] * inv;
}

// ---------------- Pass 1 (fused): mean/weights/segment + bf16 cvt + seg lists --
__global__ void row_stats_fused(const float* __restrict__ x,
                                unsigned short* __restrict__ Xb,
                                float2* __restrict__ ws2,
                                int* __restrict__ seg_rows,
                                int* __restrict__ bucket_cnt) {
  __shared__ int lcnt[NGRID];
  __shared__ int base[NGRID];
  __shared__ int lrank[RS_ROWS];
  __shared__ int lseg[RS_ROWS];
  const int tid  = threadIdx.x;          // 256 threads, 4 waves
  const int lane = tid & 63;
  const int wave = tid >> 6;
  if (tid < NGRID) lcnt[tid] = 0;
  __syncthreads();
  const int row0 = blockIdx.x * RS_ROWS;
#pragma unroll
  for (int it = 0; it < RS_ROWS / 4; ++it) {
    int r = it * 4 + wave;               // one wave per row
    int b = row0 + r;
    const float4* xr = (const float4*)(x + (size_t)b * IDIM);
    ushort4* xw = (ushort4*)(Xb + (size_t)b * IDIM);
    float4 v[4];
    float s = 0.f;
#pragma unroll
    for (int j = 0; j < 4; j++) {        // 4 independent 16B loads/lane
      v[j] = xr[lane + j * 64];
      s += v[j].x + v[j].y + v[j].z + v[j].w;
    }
#pragma unroll
    for (int j = 0; j < 4; j++) {        // bf16 copy straight from registers
      ushort4 u;
      u.x = f2bf(v[j].x); u.y = f2bf(v[j].y); u.z = f2bf(v[j].z); u.w = f2bf(v[j].w);
      xw[lane + j * 64] = u;
    }
#pragma unroll
    for (int off = 32; off; off >>= 1) s += __shfl_down(s, off, 64);
    if (lane == 0) {
      float m = s * (1.0f / (float)IDIM);
      int sI; float w0, w1;
      seg_weights(m, sI, w0, w1);
      ws2[b] = make_float2(w0, w1);
      lseg[r] = sI;
      lrank[r] = atomicAdd(&lcnt[sI], 1);   // LDS atomic: cheap
    }
  }
  __syncthreads();
  if (tid < NGRID) base[tid] = lcnt[tid] ? atomicAdd(&bucket_cnt[tid], lcnt[tid]) : 0;
  __syncthreads();
  if (tid < RS_ROWS)
    seg_rows[lseg[tid] * B_ROWS + base[lseg[tid]] + lrank[tid]] = row0 + tid;
}

// ---------------- Pass 2: coeff fp32 -> bf16, only planes actually needed ----
#define CV_BLKS_PER_PLANE (ODIM * IDIM / 4 / 256)   // 1024
__global__ void cvt_coeff(const float* __restrict__ c, unsigned short* __restrict__ cb,
                          const int* __restrict__ bucket_cnt) {
  const int g  = blockIdx.x >> 10;            // plane 0..8
  const int cI = blockIdx.x & 1023;
  bool need = bucket_cnt[g] > 0;
  if (!need && g > 0) need = bucket_cnt[g - 1] > 0;
  if (!need) return;
  int i = (g * CV_BLKS_PER_PLANE + cI) * 256 + threadIdx.x;
  float4 v = ((const float4*)c)[i];
  ushort4 o;
  o.x = f2bf(v.x); o.y = f2bf(v.y); o.z = f2bf(v.z); o.w = f2bf(v.w);
  ((ushort4*)cb)[i] = o;
}

// ---------------- Pass 3: MFMA GEMM, BM=256 x BN_eff=256, depth-2 counted vmcnt
// acc[p] = X[rows] @ coeff[seg+p]^T (K=1024); out = w0*acc0 + w1*acc1 + bias.
// 8 waves (2M x 4N): wave owns 128 rows x 64 eff cols (32 real cols x 2 planes).
// LDS 128 KB: 2 dbuf x (A 32 KB + B 32 KB). Pipeline: stage t,t+1 up front;
// per tile: vmcnt(8) (next tile's 8 loads stay in flight across the barrier!),
// raw s_barrier, compute, lgkmcnt(0)+barrier, stage t+2 into the freed buffer.
// Bank-conflict fix: 8-chunk (16B) XOR swizzle. Staging lane l writes chunk pos
// (l&7) with data chunk (l&7)^((l>>3)&7) (same 128B row span -> coalescing OK);
// readers fetch pos (h*4 + (lane>>4)) ^ (lane&7) -> banks 2-way = free (m136).
__global__ void __launch_bounds__(512, 2)
kan_gemm(const unsigned short* __restrict__ Xb,
         const unsigned short* __restrict__ Cb,
         const int* __restrict__ seg_rows,
         const int* __restrict__ bucket_cnt,
         const float2* __restrict__ ws2,
         const float* __restrict__ bias,
         float* __restrict__ out) {
  const int sub = blockIdx.x & 63;
  const int mt  = (blockIdx.x >> 6) * 8 + (sub & 7);
  const int nt  = sub >> 3;                 // 0..7 (128 real cols each)

  // Map m-tile -> (segment, local tile, bucket count) from the 9 counters.
  int seg = -1, lt = 0, cnt = 0;
  {
    int t0 = 0;
#pragma unroll
    for (int g = 0; g < NGRID; g++) {
      int c   = bucket_cnt[g];
      int ntg = (c + 255) >> 8;
      if (mt >= t0 && mt < t0 + ntg) { seg = g; lt = mt - t0; cnt = c; }
      t0 += ntg;
    }
  }
  if (seg < 0) return;                      // uniform over block: barrier-safe
  const int rlim = cnt - lt * 256;          // valid rows in this tile (1..256)
  const int* rows = seg_rows + seg * B_ROWS + lt * 256;

  __shared__ unsigned short As[2][256 * 64];   // 2 x 32 KB
  __shared__ unsigned short Bs[2][256 * 64];   // 2 x 32 KB (eff rows: p*128+col)

  const int tid  = threadIdx.x;
  const int lane = tid & 63;
  const int wave = tid >> 6;                // 0..7
  const int wm   = wave >> 2;               // 0..1 -> 128-row half
  const int wn   = wave & 3;                // 0..3 -> 32-real-col group
  const int colB0 = nt * 128;

  // ---- staging geometry: per issue, wave covers 8 rows x 64 K (8 KB/block) ----
  const int sgrow  = wave * 8 + (lane >> 3);                 // row within 64-group
  const int schunk = ((lane & 7) ^ ((lane >> 3) & 7)) * 8;   // swizzled src chunk

  int rid[4];
#pragma unroll
  for (int i = 0; i < 4; i++) {
    int idx = i * 64 + sgrow;
    rid[i] = rows[idx < rlim ? idx : rlim - 1];
  }
  const unsigned short* gA[4];
  const unsigned short* gB[4];
#pragma unroll
  for (int i = 0; i < 4; i++) {
    gA[i] = Xb + (size_t)rid[i] * IDIM + schunk;
    int s = i * 64 + sgrow;                 // eff B row: plane s>>7, col s&127
    gB[i] = Cb + ((size_t)((seg + (s >> 7)) * ODIM + colB0 + (s & 127))) * IDIM + schunk;
  }

  // ---- reader geometry ----
  const int arow = wm * 128 + (lane & 15);             // + mi*16
  const int brow = wn * 32 + (lane & 15);              // + p*128 + ni*16
  const int cs0  = (((lane >> 4) + 0) ^ (lane & 7)) * 8;  // h=0 chunk offset
  const int cs1  = (((lane >> 4) + 4) ^ (lane & 7)) * 8;  // h=1 chunk offset

  f32x4 acc[2][8][2] = {};   // [plane][mi][ni] = 128 AGPRs

#define STAGE(buf, kk) do {                                                   \
    _Pragma("unroll")                                                         \
    for (int i = 0; i < 4; i++)                                               \
      async_cp16(gA[i] + (kk), &As[buf][(i * 64 + wave * 8) * 64]);           \
    _Pragma("unroll")                                                         \
    for (int i = 0; i < 4; i++)                                               \
      async_cp16(gB[i] + (kk), &Bs[buf][(i * 64 + wave * 8) * 64]);           \
  } while (0)

#define HALF(buf, CS) do {                                                    \
    frag8 af[8]; frag8 bf[2][2];                                              \
    _Pragma("unroll")                                                         \
    for (int mi = 0; mi < 8; mi++)                                            \
      af[mi] = *(const frag8*)&As[buf][(arow + mi * 16) * 64 + (CS)];         \
    _Pragma("unroll")                                                         \
    for (int p = 0; p < 2; p++)                                               \
      _Pragma("unroll")                                                       \
      for (int ni = 0; ni < 2; ni++)                                          \
        bf[p][ni] = *(const frag8*)&Bs[buf][(brow + p * 128 + ni * 16) * 64 + (CS)]; \
    __builtin_amdgcn_s_setprio(1);                                            \
    _Pragma("unroll")                                                         \
    for (int mi = 0; mi < 8; mi++)                                            \
      _Pragma("unroll")                                                       \
      for (int p = 0; p < 2; p++)                                             \
        _Pragma("unroll")                                                     \
        for (int ni = 0; ni < 2; ni++)                                        \
          acc[p][mi][ni] = __builtin_amdgcn_mfma_f32_16x16x32_bf16(           \
              af[mi], bf[p][ni], acc[p][mi][ni], 0, 0, 0);                    \
    __builtin_amdgcn_s_setprio(0);                                            \
  } while (0)

  // ---- prologue: 2 tiles in flight (16 loads/wave) ----
  STAGE(0, 0);
  STAGE(1, 64);

#pragma unroll 2
  for (int t = 0; t < 16; ++t) {
    const int cur = t & 1;
    // Wait for tile t's 8 loads; tile t+1's 8 stay in flight across the barrier.
    if (t < 15) asm volatile("s_waitcnt vmcnt(8)" ::: "memory");
    else        asm volatile("s_waitcnt vmcnt(0)" ::: "memory");
    __builtin_amdgcn_s_barrier();
    __builtin_amdgcn_sched_barrier(0);
    HALF(cur, cs0);
    HALF(cur, cs1);
    asm volatile("s_waitcnt lgkmcnt(0)" ::: "memory");   // reads of buf[cur] done
    __builtin_amdgcn_sched_barrier(0);
    __builtin_amdgcn_s_barrier();                        // all waves done reading
    if (t < 14) STAGE(cur, (t + 2) * 64);                // refill freed buffer
  }
#undef STAGE
#undef HALF

  // ---- epilogue: D col = lane&15, row = (lane>>4)*4 + reg [m89/m91 verified] --
  int   col[2]; float bv[2];
#pragma unroll
  for (int ni = 0; ni < 2; ni++) {
    col[ni] = colB0 + wn * 32 + ni * 16 + (lane & 15);
    bv[ni]  = bias[col[ni]];
  }
#pragma unroll
  for (int mi = 0; mi < 8; mi++) {
    int irow = wm * 128 + mi * 16 + (lane >> 4) * 4;
#pragma unroll
    for (int r = 0; r < 4; r++) {
      int idx = irow + r;
      if (idx < rlim) {                     // non-padding row
        int orow = rows[idx];
        float2 w = ws2[orow];
        float* o = out + (size_t)orow * ODIM;
#pragma unroll
        for (int ni = 0; ni < 2; ni++)
          o[col[ni]] = w.x * acc[0][mi][ni][r] + w.y * acc[1][mi][ni][r] + bv[ni];
      }
    }
  }
}

// ---------------- Fallback (ws too small): slow fp32, correct ----------------
__global__ void fallback_kernel(const float* __restrict__ x, const float* __restrict__ coeff,
                                const float* __restrict__ bias, float* __restrict__ out) {
  int b = blockIdx.x;
  int tid = threadIdx.x;
  __shared__ float xs[IDIM];
  __shared__ float ps[4];
  __shared__ float mw[2];
  __shared__ int   ms;
  float4 v = ((const float4*)(x + (size_t)b * IDIM))[tid];
  ((float4*)xs)[tid] = v;
  float s = v.x + v.y + v.z + v.w;
#pragma unroll
  for (int off = 32; off; off >>= 1) s += __shfl_down(s, off, 64);
  if ((tid & 63) == 0) ps[tid >> 6] = s;
  __syncthreads();
  if (tid == 0) {
    float m = (ps[0] + ps[1] + ps[2] + ps[3]) * (1.0f / (float)IDIM);
    int sI; float w0, w1;
    seg_weights(m, sI, w0, w1);
    mw[0] = w0; mw[1] = w1; ms = sI;
  }
  __syncthreads();
  float w0 = mw[0], w1 = mw[1]; int sI = ms;
  for (int o = tid; o < ODIM; o += 256) {
    const float* c0 = coeff + ((size_t)sI * ODIM + o) * IDIM;
    const float* c1 = c0 + (size_t)ODIM * IDIM;
    float a0 = 0.f, a1 = 0.f;
    for (int i = 0; i < IDIM; i++) { a0 += xs[i] * c0[i]; a1 += xs[i] * c1[i]; }
    out[(size_t)b * ODIM + o] = w0 * a0 + w1 * a1 + bias[o];
  }
}

extern "C" void kernel_launch(void* const* d_in, const int* in_sizes, int n_in,
                              void* d_out, int out_size, void* d_ws, size_t ws_size,
                              hipStream_t stream) {
  const float* x     = (const float*)d_in[0];
  const float* coeff = (const float*)d_in[1];
  const float* bias  = (const float*)d_in[2];
  float* out = (float*)d_out;

  // Workspace layout (16B-aligned chunks)
  size_t szXb = (size_t)B_ROWS * IDIM * sizeof(unsigned short);       // 33,554,432
  size_t szCb = (size_t)NGRID * ODIM * IDIM * sizeof(unsigned short); // 18,874,368
  size_t o0 = 0;
  unsigned short* Xb = (unsigned short*)((char*)d_ws + o0); o0 += szXb;
  unsigned short* Cb = (unsigned short*)((char*)d_ws + o0); o0 += szCb;
  float2* ws2 = (float2*)((char*)d_ws + o0); o0 += (size_t)B_ROWS * 8;
  int* seg_rows = (int*)((char*)d_ws + o0); o0 += (size_t)NGRID * B_ROWS * 4;
  int* bucket_cnt = (int*)((char*)d_ws + o0); o0 += 256;

  if (ws_size < o0) {
    // Emergency slow path: no workspace required.
    fallback_kernel<<<B_ROWS, 256, 0, stream>>>(x, coeff, bias, out);
    return;
  }

  hipMemsetAsync(bucket_cnt, 0, NGRID * sizeof(int), stream);
  row_stats_fused<<<RS_BLOCKS, 256, 0, stream>>>(x, Xb, ws2, seg_rows, bucket_cnt);
  cvt_coeff<<<NGRID * CV_BLKS_PER_PLANE, 256, 0, stream>>>(coeff, Cb, bucket_cnt);
  kan_gemm<<<GEMM_BLOCKS, 512, 0, stream>>>(Xb, Cb, seg_rows, bucket_cnt, ws2, bias, out);
}

// Round 2
// 266.197 us; speedup vs baseline: 1.2197x; 1.2197x over previous
//
#include <hip/hip_runtime.h>
#include <math.h>

// Problem constants
#define B_ROWS 16384      // 8*2048 batch rows
#define IDIM   1024
#define ODIM   1024
#define NGRID  9          // NUM_SEGMENTS + 1

#define RS_BLOCKS 1024
#define RS_ROWS   (B_ROWS / RS_BLOCKS)   // 16 rows per block

// GEMM: BM=256 rows, BN=128 real cols (x2 planes -> 256 eff), BK=64, 8 waves,
// m201-style 8-phase schedule (4 phases per K-tile, 2 K-tiles per dbuf cycle).
// m-slots: max sum over buckets of ceil(cnt/256) <= 64 + 9 = 73 -> 80 slots.
#define GEMM_MSLOTS 80
#define GEMM_NT     8
#define GEMM_BLOCKS (GEMM_MSLOTS * GEMM_NT)   // 640

typedef __attribute__((ext_vector_type(8))) short frag8;   // 8 x bf16 (4 VGPRs)
typedef __attribute__((ext_vector_type(4))) float f32x4;   // MFMA accumulator

typedef __attribute__((address_space(1))) void gvoid;
typedef __attribute__((address_space(3))) void lvoid;

__device__ __forceinline__ void async_cp16(const void* g, void* l) {
  // 16B/lane global->LDS DMA; LDS dest = wave-uniform base + lane*16.
  __builtin_amdgcn_global_load_lds((gvoid*)(void*)g, (lvoid*)l, 16, 0, 0);
}

__device__ __forceinline__ unsigned short f2bf(float f) {
  union { float f; unsigned u; } v; v.f = f;
  unsigned u = v.u;
  u += 0x7fffu + ((u >> 16) & 1u);      // round-to-nearest-even
  return (unsigned short)(u >> 16);
}

// Per-row hat weights: at most 2 nonzero, at segments {s, s+1}
__device__ __forceinline__ void seg_weights(float m, int& sI, float& w0, float& w1) {
  float wsum = 0.f, wg[NGRID];
#pragma unroll
  for (int g = 0; g < NGRID; g++) {
    float gv = -1.f + 0.25f * (float)g;
    float t = 1.f - fabsf(m - gv) * 4.f;   // 1/h = 4
    wg[g] = t > 0.f ? t : 0.f;
    wsum += wg[g];
  }
  int s = (int)floorf((m + 1.f) * 4.f);
  s = s < 0 ? 0 : (s > 7 ? 7 : s);
  float inv = 1.f / (wsum + 1e-8f);
  sI = s;
  w0 = wg[s] * inv;
  w1 = wg[s + 1] * inv;
}

// ---------------- Pass 1 (fused): mean/weights/segment + bf16 cvt + seg lists --
__global__ void row_stats_fused(const float* __restrict__ x,
                                unsigned short* __restrict__ Xb,
                                float2* __restrict__ ws2,
                                int* __restrict__ seg_rows,
                                int* __restrict__ bucket_cnt) {
  __shared__ int lcnt[NGRID];
  __shared__ int base[NGRID];
  __shared__ int lrank[RS_ROWS];
  __shared__ int lseg[RS_ROWS];
  const int tid  = threadIdx.x;          // 256 threads, 4 waves
  const int lane = tid & 63;
  const int wave = tid >> 6;
  if (tid < NGRID) lcnt[tid] = 0;
  __syncthreads();
  const int row0 = blockIdx.x * RS_ROWS;
#pragma unroll
  for (int it = 0; it < RS_ROWS / 4; ++it) {
    int r = it * 4 + wave;               // one wave per row
    int b = row0 + r;
    const float4* xr = (const float4*)(x + (size_t)b * IDIM);
    ushort4* xw = (ushort4*)(Xb + (size_t)b * IDIM);
    float4 v[4];
    float s = 0.f;
#pragma unroll
    for (int j = 0; j < 4; j++) {        // 4 independent 16B loads/lane
      v[j] = xr[lane + j * 64];
      s += v[j].x + v[j].y + v[j].z + v[j].w;
    }
#pragma unroll
    for (int j = 0; j < 4; j++) {        // bf16 copy straight from registers
      ushort4 u;
      u.x = f2bf(v[j].x); u.y = f2bf(v[j].y); u.z = f2bf(v[j].z); u.w = f2bf(v[j].w);
      xw[lane + j * 64] = u;
    }
#pragma unroll
    for (int off = 32; off; off >>= 1) s += __shfl_down(s, off, 64);
    if (lane == 0) {
      float m = s * (1.0f / (float)IDIM);
      int sI; float w0, w1;
      seg_weights(m, sI, w0, w1);
      ws2[b] = make_float2(w0, w1);
      lseg[r] = sI;
      lrank[r] = atomicAdd(&lcnt[sI], 1);   // LDS atomic: cheap
    }
  }
  __syncthreads();
  if (tid < NGRID) base[tid] = lcnt[tid] ? atomicAdd(&bucket_cnt[tid], lcnt[tid]) : 0;
  __syncthreads();
  if (tid < RS_ROWS)
    seg_rows[lseg[tid] * B_ROWS + base[lseg[tid]] + lrank[tid]] = row0 + tid;
}

// ---------------- Pass 2: coeff fp32 -> bf16, only planes actually needed ----
#define CV_BLKS_PER_PLANE (ODIM * IDIM / 4 / 256)   // 1024
__global__ void cvt_coeff(const float* __restrict__ c, unsigned short* __restrict__ cb,
                          const int* __restrict__ bucket_cnt) {
  const int g  = blockIdx.x >> 10;            // plane 0..8
  const int cI = blockIdx.x & 1023;
  bool need = bucket_cnt[g] > 0;
  if (!need && g > 0) need = bucket_cnt[g - 1] > 0;
  if (!need) return;
  int i = (g * CV_BLKS_PER_PLANE + cI) * 256 + threadIdx.x;
  float4 v = ((const float4*)c)[i];
  ushort4 o;
  o.x = f2bf(v.x); o.y = f2bf(v.y); o.z = f2bf(v.z); o.w = f2bf(v.w);
  ((ushort4*)cb)[i] = o;
}

// ---------------- Pass 3: MFMA GEMM, 8-phase m201-style schedule --------------
// acc[p] = X[rows] @ coeff[seg+p]^T (K=1024); out = w0*acc0 + w1*acc1 + bias.
// 8 waves (2M x 4N): wave owns rows {wm*64..+63} u {128+wm*64..+63} and real
// cols {wn*32..+31} in both planes. Eff-B row e = plane*128 + realcol.
// LDS: As[2][256x64] + Bs[2][256x64] = 128 KB + 1 KB scratch.
// Per K-tile t, 4 phases (barrier-delimited). Stage sequence per tile:
//   p0: A1(t+1)->other buf, p1: A0(t+2)->cur buf, p2: B0(t+2), p3: B1(t+2)
// (each "half" = 128 rows x 64 k = 16 KB = 2 global_load_lds per wave).
// Hazards: every stage target's last LDS read completed >= 1 barrier earlier;
// every staged half is consumed >= 6 phases after issue. vmcnt(10) at end of
// p0/p1/p3 retires exactly the half the NEXT phase reads (7 halves = 14 loads
// max in flight; never drains to 0). Tail tiles stage dummies into scratch so
// vmcnt counts stay uniform.
// Swizzle: row r (mod 8), logical 16B chunk (kh,q) stored at chunk
// (kh^(r&1))*4 + (q^((r>>1)&3)) -> every 8-lane b128 phase covers 32 banks.
__global__ void __launch_bounds__(512, 2)
kan_gemm(const unsigned short* __restrict__ Xb,
         const unsigned short* __restrict__ Cb,
         const int* __restrict__ seg_rows,
         const int* __restrict__ bucket_cnt,
         const float2* __restrict__ ws2,
         const float* __restrict__ bias,
         float* __restrict__ out) {
  const int sub = blockIdx.x & 63;
  const int mt  = (blockIdx.x >> 6) * 8 + (sub & 7);
  const int nt  = sub >> 3;                 // 0..7 (128 real cols each)

  int seg = -1, lt = 0, cnt = 0;
  {
    int t0 = 0;
#pragma unroll
    for (int g = 0; g < NGRID; g++) {
      int c   = bucket_cnt[g];
      int ntg = (c + 255) >> 8;
      if (mt >= t0 && mt < t0 + ntg) { seg = g; lt = mt - t0; cnt = c; }
      t0 += ntg;
    }
  }
  if (seg < 0) return;                      // uniform over block: barrier-safe
  const int rlim = cnt - lt * 256;          // valid rows in this tile (1..256)
  const int* rows = seg_rows + seg * B_ROWS + lt * 256;

  __shared__ unsigned short As[2][256 * 64];   // 2 x 32 KB
  __shared__ unsigned short Bs[2][256 * 64];   // 2 x 32 KB
  __shared__ unsigned short scratch[512];      // dummy stage target (1 KB)

  const int tid  = threadIdx.x;
  const int lane = tid & 63;
  const int wave = tid >> 6;                // 0..7
  const int wm   = wave >> 2;               // 0..1
  const int wn   = wave & 3;                // 0..3
  const int colB0 = nt * 128;

  // ---- staging geometry: one half-tile = 128 rows x 64 k; wave covers rows
  //      [wave*16, wave*16+16) of the half via 2 issues of 8 rows each. ----
  const int srow = lane >> 3;               // 0..7 within the 8-row issue
  const int sc   = lane & 7;                // LDS chunk position
  // source chunk = SW(srow, sc): involution per row
  const int swc  = (((sc >> 2) ^ (srow & 1)) << 2) | ((sc & 3) ^ ((srow >> 1) & 3));
  const unsigned swkB = (unsigned)swc * 16; // byte offset within 128B row

  unsigned aOff[2][2], bOff[2][2];
#pragma unroll
  for (int h = 0; h < 2; h++)
#pragma unroll
    for (int i = 0; i < 2; i++) {
      int idx = h * 128 + wave * 16 + i * 8 + srow;
      int rid = rows[idx < rlim ? idx : rlim - 1];
      aOff[h][i] = (unsigned)rid * (IDIM * 2) + swkB;
      int realcol = wave * 16 + i * 8 + srow;          // plane = h
      bOff[h][i] = (unsigned)((seg + h) * ODIM + colB0 + realcol) * (IDIM * 2) + swkB;
    }

  // ---- reader geometry: frag8 at row (.. + lane&15), logical (kh, q=lane>>4)
  int rofs[2];
#pragma unroll
  for (int kh = 0; kh < 2; kh++)
    rofs[kh] = ((((kh ^ (lane & 1)) << 2) | (((lane >> 4) & 3) ^ ((lane >> 1) & 3))) ) * 8;

  f32x4 acc[8][4] = {};    // [mi][ni]; mi = mh*4+mi', ni = nh*2+ni' (nh = plane)
  frag8 af[8];             // current mh: [mi'*2 + kh]
  frag8 bf[8];             // all 4 ni:   [ni*2 + kh]

#define STAGE_A(B, T, H) do {                                                  \
    const int tt_ = (T);                                                       \
    _Pragma("unroll")                                                          \
    for (int i_ = 0; i_ < 2; i_++) {                                           \
      unsigned short* dst_ = (tt_ < 16) ? &As[B][((H) * 128 + wave * 16 + i_ * 8) * 64] : scratch; \
      const char* src_ = (const char*)Xb + (tt_ < 16 ? (size_t)(aOff[H][i_] + (unsigned)tt_ * 128) : (size_t)swkB); \
      async_cp16(src_, dst_);                                                  \
    }                                                                          \
  } while (0)

#define STAGE_B(B, T, H) do {                                                  \
    const int tt_ = (T);                                                       \
    _Pragma("unroll")                                                          \
    for (int i_ = 0; i_ < 2; i_++) {                                           \
      unsigned short* dst_ = (tt_ < 16) ? &Bs[B][((H) * 128 + wave * 16 + i_ * 8) * 64] : scratch; \
      const char* src_ = (const char*)Cb + (tt_ < 16 ? (size_t)(bOff[H][i_] + (unsigned)tt_ * 128) : (size_t)swkB); \
      async_cp16(src_, dst_);                                                  \
    }                                                                          \
  } while (0)

#define LOAD_AF(B, MH) do {                                                    \
    _Pragma("unroll")                                                          \
    for (int mi_ = 0; mi_ < 4; mi_++)                                          \
      _Pragma("unroll")                                                        \
      for (int kh_ = 0; kh_ < 2; kh_++)                                        \
        af[mi_ * 2 + kh_] = *(const frag8*)&As[B][((MH) * 128 + wm * 64 + mi_ * 16 + (lane & 15)) * 64 + rofs[kh_]]; \
  } while (0)

#define LOAD_BF(B, NH) do {                                                    \
    _Pragma("unroll")                                                          \
    for (int ni_ = 0; ni_ < 2; ni_++)                                          \
      _Pragma("unroll")                                                        \
      for (int kh_ = 0; kh_ < 2; kh_++)                                        \
        bf[((NH) * 2 + ni_) * 2 + kh_] = *(const frag8*)&Bs[B][((NH) * 128 + wn * 32 + ni_ * 16 + (lane & 15)) * 64 + rofs[kh_]]; \
  } while (0)

#define MFMA_Q(MH, NH) do {                                                    \
    __builtin_amdgcn_s_setprio(1);                                             \
    _Pragma("unroll")                                                          \
    for (int mi_ = 0; mi_ < 4; mi_++)                                          \
      _Pragma("unroll")                                                        \
      for (int ni_ = 0; ni_ < 2; ni_++)                                        \
        _Pragma("unroll")                                                      \
        for (int kh_ = 0; kh_ < 2; kh_++)                                      \
          acc[(MH) * 4 + mi_][(NH) * 2 + ni_] = __builtin_amdgcn_mfma_f32_16x16x32_bf16( \
              af[mi_ * 2 + kh_], bf[((NH) * 2 + ni_) * 2 + kh_],               \
              acc[(MH) * 4 + mi_][(NH) * 2 + ni_], 0, 0, 0);                   \
    __builtin_amdgcn_s_setprio(0);                                             \
  } while (0)

#define VM10 asm volatile("s_waitcnt vmcnt(10)" ::: "memory")
#define BAR  asm volatile("s_barrier" ::: "memory")

  // ---- prologue: 7 half-tiles in exact order (counts feed the vmcnt scheme) --
  STAGE_A(0, 0, 0);   // A0(0)
  STAGE_B(0, 0, 0);   // B0(0)
  STAGE_B(0, 0, 1);   // B1(0)
  STAGE_A(0, 0, 1);   // A1(0)
  STAGE_A(1, 1, 0);   // A0(1)
  STAGE_B(1, 1, 0);   // B0(1)
  STAGE_B(1, 1, 1);   // B1(1)
  VM10;               // A0(0), B0(0) landed (own slice); barrier => block-wide
  BAR;

#pragma unroll 2
  for (int t = 0; t < 16; ++t) {
    const int buf  = t & 1;
    const int nbuf = buf ^ 1;
    // ---- p0: read af(mh0)+bf(nh0); stage A1(t+1); gate B1(t) for p1 ----
    LOAD_AF(buf, 0);
    LOAD_BF(buf, 0);
    STAGE_A(nbuf, t + 1, 1);
    VM10; BAR;
    MFMA_Q(0, 0);
    BAR;
    // ---- p1: read bf(nh1); stage A0(t+2); gate A1(t) for p2 ----
    LOAD_BF(buf, 1);
    STAGE_A(buf, t + 2, 0);
    VM10; BAR;
    MFMA_Q(0, 1);
    BAR;
    // ---- p2: read af(mh1); stage B0(t+2) ----
    LOAD_AF(buf, 1);
    STAGE_B(buf, t + 2, 0);
    BAR;
    MFMA_Q(1, 1);
    BAR;
    // ---- p3: no reads; stage B1(t+2); gate A0(t+1),B0(t+1) for next p0 ----
    STAGE_B(buf, t + 2, 1);
    MFMA_Q(1, 0);
    VM10; BAR;
  }
#undef STAGE_A
#undef STAGE_B
#undef LOAD_AF
#undef LOAD_BF
#undef MFMA_Q

  // ---- epilogue: D col = lane&15, row = (lane>>4)*4 + reg [m89/m91 verified] --
  int   col[2]; float bv[2];
#pragma unroll
  for (int nc = 0; nc < 2; nc++) {
    col[nc] = colB0 + wn * 32 + nc * 16 + (lane & 15);
    bv[nc]  = bias[col[nc]];
  }
#pragma unroll
  for (int mi = 0; mi < 8; mi++) {
    int irow = (mi >> 2) * 128 + wm * 64 + (mi & 3) * 16 + (lane >> 4) * 4;
#pragma unroll
    for (int r = 0; r < 4; r++) {
      int idx = irow + r;
      if (idx < rlim) {                     // non-padding row
        int orow = rows[idx];
        float2 w = ws2[orow];
        float* o = out + (size_t)orow * ODIM;
#pragma unroll
        for (int nc = 0; nc < 2; nc++)
          o[col[nc]] = w.x * acc[mi][nc][r] + w.y * acc[mi][2 + nc][r] + bv[nc];
      }
    }
  }
}

// ---------------- Fallback (ws too small): slow fp32, correct ----------------
__global__ void fallback_kernel(const float* __restrict__ x, const float* __restrict__ coeff,
                                const float* __restrict__ bias, float* __restrict__ out) {
  int b = blockIdx.x;
  int tid = threadIdx.x;
  __shared__ float xs[IDIM];
  __shared__ float ps[4];
  __shared__ float mw[2];
  __shared__ int   ms;
  float4 v = ((const float4*)(x + (size_t)b * IDIM))[tid];
  ((float4*)xs)[tid] = v;
  float s = v.x + v.y + v.z + v.w;
#pragma unroll
  for (int off = 32; off; off >>= 1) s += __shfl_down(s, off, 64);
  if ((tid & 63) == 0) ps[tid >> 6] = s;
  __syncthreads();
  if (tid == 0) {
    float m = (ps[0] + ps[1] + ps[2] + ps[3]) * (1.0f / (float)IDIM);
    int sI; float w0, w1;
    seg_weights(m, sI, w0, w1);
    mw[0] = w0; mw[1] = w1; ms = sI;
  }
  __syncthreads();
  float w0 = mw[0], w1 = mw[1]; int sI = ms;
  for (int o = tid; o < ODIM; o += 256) {
    const float* c0 = coeff + ((size_t)sI * ODIM + o) * IDIM;
    const float* c1 = c0 + (size_t)ODIM * IDIM;
    float a0 = 0.f, a1 = 0.f;
    for (int i = 0; i < IDIM; i++) { a0 += xs[i] * c0[i]; a1 += xs[i] * c1[i]; }
    out[(size_t)b * ODIM + o] = w0 * a0 + w1 * a1 + bias[o];
  }
}

extern "C" void kernel_launch(void* const* d_in, const int* in_sizes, int n_in,
                              void* d_out, int out_size, void* d_ws, size_t ws_size,
                              hipStream_t stream) {
  const float* x     = (const float*)d_in[0];
  const float* coeff = (const float*)d_in[1];
  const float* bias  = (const float*)d_in[2];
  float* out = (float*)d_out;

  // Workspace layout (16B-aligned chunks)
  size_t szXb = (size_t)B_ROWS * IDIM * sizeof(unsigned short);       // 33,554,432
  size_t szCb = (size_t)NGRID * ODIM * IDIM * sizeof(unsigned short); // 18,874,368
  size_t o0 = 0;
  unsigned short* Xb = (unsigned short*)((char*)d_ws + o0); o0 += szXb;
  unsigned short* Cb = (unsigned short*)((char*)d_ws + o0); o0 += szCb;
  float2* ws2 = (float2*)((char*)d_ws + o0); o0 += (size_t)B_ROWS * 8;
  int* seg_rows = (int*)((char*)d_ws + o0); o0 += (size_t)NGRID * B_ROWS * 4;
  int* bucket_cnt = (int*)((char*)d_ws + o0); o0 += 256;

  if (ws_size < o0) {
    // Emergency slow path: no workspace required.
    fallback_kernel<<<B_ROWS, 256, 0, stream>>>(x, coeff, bias, out);
    return;
  }

  hipMemsetAsync(bucket_cnt, 0, NGRID * sizeof(int), stream);
  row_stats_fused<<<RS_BLOCKS, 256, 0, stream>>>(x, Xb, ws2, seg_rows, bucket_cnt);
  cvt_coeff<<<NGRID * CV_BLKS_PER_PLANE, 256, 0, stream>>>(coeff, Cb, bucket_cnt);
  kan_gemm<<<GEMM_BLOCKS, 512, 0, stream>>>(Xb, Cb, seg_rows, bucket_cnt, ws2, bias, out);
}

// Round 3
// 254.117 us; speedup vs baseline: 1.2777x; 1.0475x over previous
//
#include <hip/hip_runtime.h>
#include <math.h>

// Problem constants
#define B_ROWS 16384      // 8*2048 batch rows
#define IDIM   1024
#define ODIM   1024
#define NGRID  9          // NUM_SEGMENTS + 1

#define RS_BLOCKS 1024
#define RS_ROWS   (B_ROWS / RS_BLOCKS)   // 16 rows per block

// GEMM: BM=128 rows, BN=128 real cols (x2 planes -> 256 eff), BK=64, 4 waves.
// Wave tile: mi=8 (all 128 rows) x ni=4 (32 real cols x 2 planes).
// LDS model (cyc/MFMA, serial 256B/cyc read + 128B/cyc write):
//   reads 384B -> 1.5, writes 192B -> 1.5, total 3.0 vs round-0's 4.0 -> 40% ceiling.
// m-slots: max sum over buckets of ceil(cnt/128) <= 128 + 8 = 136.
// Swizzle windows of 64 ids: (sub&7)=m-class (same XCD via round-robin),
// sub>>3 = n-tile (0..7) -> the 8 n-blocks of one m-tile share an XCD L2.
#define GEMM_MSLOTS 136
#define GEMM_NT     8
#define GEMM_BLOCKS ((GEMM_MSLOTS / 8) * 64)   // 17 windows x 64 = 1088

typedef __attribute__((ext_vector_type(8))) short frag8;   // 8 x bf16 (4 VGPRs)
typedef __attribute__((ext_vector_type(4))) float f32x4;   // MFMA accumulator

typedef __attribute__((address_space(1))) void gvoid;
typedef __attribute__((address_space(3))) void lvoid;

__device__ __forceinline__ void async_cp16(const void* g, void* l) {
  // 16B/lane global->LDS DMA; LDS dest = wave-uniform base + lane*16.
  // Global side is a normal per-lane VMEM address (gather OK).
  __builtin_amdgcn_global_load_lds((gvoid*)(void*)g, (lvoid*)l, 16, 0, 0);
}

__device__ __forceinline__ unsigned short f2bf(float f) {
  union { float f; unsigned u; } v; v.f = f;
  unsigned u = v.u;
  u += 0x7fffu + ((u >> 16) & 1u);      // round-to-nearest-even
  return (unsigned short)(u >> 16);
}

// Per-row hat weights: at most 2 nonzero, at segments {s, s+1}
__device__ __forceinline__ void seg_weights(float m, int& sI, float& w0, float& w1) {
  float wsum = 0.f, wg[NGRID];
#pragma unroll
  for (int g = 0; g < NGRID; g++) {
    float gv = -1.f + 0.25f * (float)g;
    float t = 1.f - fabsf(m - gv) * 4.f;   // 1/h = 4
    wg[g] = t > 0.f ? t : 0.f;
    wsum += wg[g];
  }
  int s = (int)floorf((m + 1.f) * 4.f);
  s = s < 0 ? 0 : (s > 7 ? 7 : s);
  float inv = 1.f / (wsum + 1e-8f);
  sI = s;
  w0 = wg[s] * inv;
  w1 = wg[s + 1] * inv;
}

// ---------------- Pass 1 (fused): mean/weights/segment + bf16 cvt + seg lists --
__global__ void row_stats_fused(const float* __restrict__ x,
                                unsigned short* __restrict__ Xb,
                                float2* __restrict__ ws2,
                                int* __restrict__ seg_rows,
                                int* __restrict__ bucket_cnt) {
  __shared__ int lcnt[NGRID];
  __shared__ int base[NGRID];
  __shared__ int lrank[RS_ROWS];
  __shared__ int lseg[RS_ROWS];
  const int tid  = threadIdx.x;          // 256 threads, 4 waves
  const int lane = tid & 63;
  const int wave = tid >> 6;
  if (tid < NGRID) lcnt[tid] = 0;
  __syncthreads();
  const int row0 = blockIdx.x * RS_ROWS;
#pragma unroll
  for (int it = 0; it < RS_ROWS / 4; ++it) {
    int r = it * 4 + wave;               // one wave per row
    int b = row0 + r;
    const float4* xr = (const float4*)(x + (size_t)b * IDIM);
    ushort4* xw = (ushort4*)(Xb + (size_t)b * IDIM);
    float4 v[4];
    float s = 0.f;
#pragma unroll
    for (int j = 0; j < 4; j++) {        // 4 independent 16B loads/lane
      v[j] = xr[lane + j * 64];
      s += v[j].x + v[j].y + v[j].z + v[j].w;
    }
#pragma unroll
    for (int j = 0; j < 4; j++) {        // bf16 copy straight from registers
      ushort4 u;
      u.x = f2bf(v[j].x); u.y = f2bf(v[j].y); u.z = f2bf(v[j].z); u.w = f2bf(v[j].w);
      xw[lane + j * 64] = u;
    }
#pragma unroll
    for (int off = 32; off; off >>= 1) s += __shfl_down(s, off, 64);
    if (lane == 0) {
      float m = s * (1.0f / (float)IDIM);
      int sI; float w0, w1;
      seg_weights(m, sI, w0, w1);
      ws2[b] = make_float2(w0, w1);
      lseg[r] = sI;
      lrank[r] = atomicAdd(&lcnt[sI], 1);   // LDS atomic: cheap
    }
  }
  __syncthreads();
  if (tid < NGRID) base[tid] = lcnt[tid] ? atomicAdd(&bucket_cnt[tid], lcnt[tid]) : 0;
  __syncthreads();
  if (tid < RS_ROWS)
    seg_rows[lseg[tid] * B_ROWS + base[lseg[tid]] + lrank[tid]] = row0 + tid;
}

// ---------------- Pass 2: coeff fp32 -> bf16, only planes actually needed ----
#define CV_BLKS_PER_PLANE (ODIM * IDIM / 4 / 256)   // 1024
__global__ void cvt_coeff(const float* __restrict__ c, unsigned short* __restrict__ cb,
                          const int* __restrict__ bucket_cnt) {
  const int g  = blockIdx.x >> 10;            // plane 0..8
  const int cI = blockIdx.x & 1023;
  bool need = bucket_cnt[g] > 0;
  if (!need && g > 0) need = bucket_cnt[g - 1] > 0;
  if (!need) return;
  int i = (g * CV_BLKS_PER_PLANE + cI) * 256 + threadIdx.x;
  float4 v = ((const float4*)c)[i];
  ushort4 o;
  o.x = f2bf(v.x); o.y = f2bf(v.y); o.z = f2bf(v.z); o.w = f2bf(v.w);
  ((ushort4*)cb)[i] = o;
}

// ---------------- Pass 3: MFMA GEMM, BM=128 x BN_eff=256, fat waves ----------
// acc[p] = X[rows] @ coeff[seg+p]^T (K=1024); out = w0*acc0 + w1*acc1 + bias.
// 4 waves (1M x 4N): each wave owns ALL 128 rows x 32 real cols x 2 planes
// (mi=8, ni=4) -> LDS reads 384B/MFMA vs round-0's 512, writes 192 vs 256.
// Single-buffer 2-barrier K-loop (round-0 proven); 48 KB LDS -> 2 blocks/CU,
// cross-block overlap hides the staging drain.
// Bank-conflict fix (round-0 proven, 0 conflicts measured): k-chunk XOR
// swizzle. Staging lane l loads global chunk (l&3)^((l>>3)&3) of its row
// (same 64 B span -> coalescing unchanged); readers fetch chunk q^((r>>1)&3).
// Read bank = 16(r&1)+4(q^f(r)) -> every 16-lane phase = 2 lanes/bank = free.
__global__ void __launch_bounds__(256, 2)
kan_gemm(const unsigned short* __restrict__ Xb,
         const unsigned short* __restrict__ Cb,
         const int* __restrict__ seg_rows,
         const int* __restrict__ bucket_cnt,
         const float2* __restrict__ ws2,
         const float* __restrict__ bias,
         float* __restrict__ out) {
  // XCD swizzle: sub&7 -> m-tile class (same XCD), sub>>3 -> n-tile (0..7).
  const int sub = blockIdx.x & 63;
  const int mt  = (blockIdx.x >> 6) * 8 + (sub & 7);
  const int nt  = sub >> 3;

  // Map m-tile -> (segment, local tile, bucket count) from the 9 counters.
  int seg = -1, lt = 0, cnt = 0;
  {
    int t0 = 0;
#pragma unroll
    for (int g = 0; g < NGRID; g++) {
      int c   = bucket_cnt[g];
      int ntg = (c + 127) >> 7;
      if (mt >= t0 && mt < t0 + ntg) { seg = g; lt = mt - t0; cnt = c; }
      t0 += ntg;
    }
  }
  if (seg < 0) return;                      // uniform over block: barrier-safe
  const int rlim = cnt - lt * 128;          // valid rows in this tile (1..128)
  const int* rows = seg_rows + seg * B_ROWS + lt * 128;

  __shared__ unsigned short As[2][128 * 32];   // 2 x 8 KB  (h-halves of BK=64)
  __shared__ unsigned short Bs[2][256 * 32];   // 2 x 16 KB (eff rows p*128+col)

  const int tid  = threadIdx.x;
  const int lane = tid & 63;
  const int wave = tid >> 6;                // 0..3 = wn (N-group)
  const int wn   = wave;
  const int colB0 = nt * 128;

  // ---- staging geometry: one issue = 16 rows x 32k-half (1 KB) ----
  const int srow16 = lane >> 2;                              // row in 16-group
  const int schunk = ((lane & 3) ^ ((lane >> 3) & 3)) * 8;   // swizzled src chunk

  // A: 8 issues of 16 rows -> 2 per wave. Clamp padding lanes (masked later).
  const unsigned short* gA[2];
#pragma unroll
  for (int i = 0; i < 2; i++) {
    int idx = (wave * 2 + i) * 16 + srow16;
    int rid = rows[idx < rlim ? idx : rlim - 1];
    gA[i] = Xb + (size_t)rid * IDIM + schunk;
  }
  // B: 16 issues of 16 eff rows -> 4 per wave. eff row e = plane*128 + realcol.
  const unsigned short* gB[4];
#pragma unroll
  for (int i = 0; i < 4; i++) {
    int e = (wave * 4 + i) * 16 + srow16;
    gB[i] = Cb + ((size_t)((seg + (e >> 7)) * ODIM + colB0 + (e & 127))) * IDIM + schunk;
  }

  // ---- reader geometry: un-swizzle for row r=lane&15, chunk q=lane>>4 ----
  const int rswz = (((lane >> 4) ^ ((lane >> 1) & 3))) * 8;

  f32x4 acc[8][4] = {};    // [mi][ni]; ni = plane*2 + nc -> 128 AGPRs

  for (int kk = 0; kk < IDIM; kk += 64) {
    __syncthreads();                        // prior iter's LDS reads complete
#pragma unroll
    for (int h = 0; h < 2; h++) {
      int ko = kk + h * 32;
#pragma unroll
      for (int i = 0; i < 2; i++)
        async_cp16(gA[i] + ko, &As[h][(wave * 2 + i) * 512]);
#pragma unroll
      for (int i = 0; i < 4; i++)
        async_cp16(gB[i] + ko, &Bs[h][(wave * 4 + i) * 512]);
    }
    __syncthreads();                        // staging visible (vmcnt drain at barrier)

#pragma unroll
    for (int h = 0; h < 2; h++) {
      frag8 af[8], bfr[4];
#pragma unroll
      for (int mi = 0; mi < 8; mi++)
        af[mi] = *(const frag8*)&As[h][(mi * 16 + (lane & 15)) * 32 + rswz];
#pragma unroll
      for (int ni = 0; ni < 4; ni++) {
        int e = (ni >> 1) * 128 + wn * 32 + (ni & 1) * 16 + (lane & 15);
        bfr[ni] = *(const frag8*)&Bs[h][e * 32 + rswz];
      }
#pragma unroll
      for (int mi = 0; mi < 8; mi++)
#pragma unroll
        for (int ni = 0; ni < 4; ni++)
          acc[mi][ni] = __builtin_amdgcn_mfma_f32_16x16x32_bf16(af[mi], bfr[ni], acc[mi][ni], 0, 0, 0);
    }
  }

  // ---- epilogue: D col = lane&15, row = (lane>>4)*4 + reg [m89/m91 verified] --
  int   col[2]; float bv[2];
#pragma unroll
  for (int nc = 0; nc < 2; nc++) {
    col[nc] = colB0 + wn * 32 + nc * 16 + (lane & 15);
    bv[nc]  = bias[col[nc]];
  }
#pragma unroll
  for (int mi = 0; mi < 8; mi++) {
    int irow = mi * 16 + (lane >> 4) * 4;
#pragma unroll
    for (int r = 0; r < 4; r++) {
      int idx = irow + r;
      if (idx < rlim) {                     // non-padding row
        int orow = rows[idx];
        float2 w = ws2[orow];
        float* o = out + (size_t)orow * ODIM;
#pragma unroll
        for (int nc = 0; nc < 2; nc++)
          o[col[nc]] = w.x * acc[mi][nc][r] + w.y * acc[mi][2 + nc][r] + bv[nc];
      }
    }
  }
}

// ---------------- Fallback (ws too small): slow fp32, correct ----------------
__global__ void fallback_kernel(const float* __restrict__ x, const float* __restrict__ coeff,
                                const float* __restrict__ bias, float* __restrict__ out) {
  int b = blockIdx.x;
  int tid = threadIdx.x;
  __shared__ float xs[IDIM];
  __shared__ float ps[4];
  __shared__ float mw[2];
  __shared__ int   ms;
  float4 v = ((const float4*)(x + (size_t)b * IDIM))[tid];
  ((float4*)xs)[tid] = v;
  float s = v.x + v.y + v.z + v.w;
#pragma unroll
  for (int off = 32; off; off >>= 1) s += __shfl_down(s, off, 64);
  if ((tid & 63) == 0) ps[tid >> 6] = s;
  __syncthreads();
  if (tid == 0) {
    float m = (ps[0] + ps[1] + ps[2] + ps[3]) * (1.0f / (float)IDIM);
    int sI; float w0, w1;
    seg_weights(m, sI, w0, w1);
    mw[0] = w0; mw[1] = w1; ms = sI;
  }
  __syncthreads();
  float w0 = mw[0], w1 = mw[1]; int sI = ms;
  for (int o = tid; o < ODIM; o += 256) {
    const float* c0 = coeff + ((size_t)sI * ODIM + o) * IDIM;
    const float* c1 = c0 + (size_t)ODIM * IDIM;
    float a0 = 0.f, a1 = 0.f;
    for (int i = 0; i < IDIM; i++) { a0 += xs[i] * c0[i]; a1 += xs[i] * c1[i]; }
    out[(size_t)b * ODIM + o] = w0 * a0 + w1 * a1 + bias[o];
  }
}

extern "C" void kernel_launch(void* const* d_in, const int* in_sizes, int n_in,
                              void* d_out, int out_size, void* d_ws, size_t ws_size,
                              hipStream_t stream) {
  const float* x     = (const float*)d_in[0];
  const float* coeff = (const float*)d_in[1];
  const float* bias  = (const float*)d_in[2];
  float* out = (float*)d_out;

  // Workspace layout (16B-aligned chunks)
  size_t szXb = (size_t)B_ROWS * IDIM * sizeof(unsigned short);       // 33,554,432
  size_t szCb = (size_t)NGRID * ODIM * IDIM * sizeof(unsigned short); // 18,874,368
  size_t o0 = 0;
  unsigned short* Xb = (unsigned short*)((char*)d_ws + o0); o0 += szXb;
  unsigned short* Cb = (unsigned short*)((char*)d_ws + o0); o0 += szCb;
  float2* ws2 = (float2*)((char*)d_ws + o0); o0 += (size_t)B_ROWS * 8;
  int* seg_rows = (int*)((char*)d_ws + o0); o0 += (size_t)NGRID * B_ROWS * 4;
  int* bucket_cnt = (int*)((char*)d_ws + o0); o0 += 256;

  if (ws_size < o0) {
    // Emergency slow path: no workspace required.
    fallback_kernel<<<B_ROWS, 256, 0, stream>>>(x, coeff, bias, out);
    return;
  }

  hipMemsetAsync(bucket_cnt, 0, NGRID * sizeof(int), stream);
  row_stats_fused<<<RS_BLOCKS, 256, 0, stream>>>(x, Xb, ws2, seg_rows, bucket_cnt);
  cvt_coeff<<<NGRID * CV_BLKS_PER_PLANE, 256, 0, stream>>>(coeff, Cb, bucket_cnt);
  kan_gemm<<<GEMM_BLOCKS, 256, 0, stream>>>(Xb, Cb, seg_rows, bucket_cnt, ws2, bias, out);
}